// Round 1
// baseline (1035.981 us; speedup 1.0000x reference)
//
#include <hip/hip_runtime.h>

#define T_STEPS 512
#define BATCH   2048
#define ISZ     128
#define HSZ     64
#define VSZ     128
#define ZSZ     192   // I + H
#define GSZ     256   // 4H

#define MBLK    16    // batch rows per block
#define NTHREADS 512  // 8 waves
#define ZLD     200   // z_lds row stride in bf16 elems (192 + 8 pad)
#define GLD     68    // g_lds row stride (floats)
#define CLD     68
#define LLD     132

typedef __attribute__((ext_vector_type(8))) short bf16x8;
typedef __attribute__((ext_vector_type(4))) float f32x4;
typedef __attribute__((ext_vector_type(4))) unsigned short u16x4;

__device__ __forceinline__ unsigned short f2bf(float x) {
  union { float f; unsigned int u; } v; v.f = x;
  unsigned int u = v.u;
  unsigned int r = (u + 0x7fffu + ((u >> 16) & 1u)) >> 16;  // RNE
  return (unsigned short)r;
}

__device__ __forceinline__ float fsigmoid(float x) {
  return 1.0f / (1.0f + __expf(-x));
}

__device__ __forceinline__ float ftanh(float x) {
  x = fminf(fmaxf(x, -15.0f), 15.0f);
  float e = __expf(-2.0f * x);
  return (1.0f - e) / (1.0f + e);
}

__global__ __launch_bounds__(NTHREADS) void lstm_kernel(
    const float* __restrict__ x,
    const float* __restrict__ h0,
    const float* __restrict__ c0,
    const float* __restrict__ Wf,  const float* __restrict__ bf_,
    const float* __restrict__ Wif, const float* __restrict__ bif_,
    const float* __restrict__ Wic, const float* __restrict__ bic_,
    const float* __restrict__ Wo,  const float* __restrict__ bo_,
    const float* __restrict__ Wout, const float* __restrict__ bout_,
    float* __restrict__ out)
{
  __shared__ unsigned short z_lds[MBLK * ZLD];        // bf16 z tile [16][192]
  __shared__ float g_lds[4 * MBLK * GLD];             // activated gates [4][16][64]
  __shared__ float c_lds[MBLK * CLD];                 // cell state fp32
  __shared__ float l_lds[MBLK * LLD];                 // logits fp32

  const int tid  = threadIdx.x;
  const int wv   = tid >> 6;     // 0..7
  const int ln   = tid & 63;
  const int lrow = ln & 15;      // M/N index within MFMA fragment
  const int lkg  = ln >> 4;      // k-group
  const int b0   = blockIdx.x * MBLK;

  // ---- one-time: weight fragments into registers ----
  const float* Wg_[4] = {Wf, Wif, Wic, Wo};
  const float* bg_[4] = {bf_, bif_, bic_, bo_};
  const int gate     = wv >> 1;            // which gate this wave computes
  const int gate_row = 32 * (wv & 1);      // 0 or 32 within the gate's 64 rows
  const float* Wgate = Wg_[gate];
  const float* bgate = bg_[gate];

  bf16x8 fragWg[6][2];   // [kf over K=192][nf over wave's 2x16 cols]
#pragma unroll
  for (int kf = 0; kf < 6; ++kf) {
#pragma unroll
    for (int nf = 0; nf < 2; ++nf) {
      int j = gate_row + 16 * nf + lrow;                    // row of W (gate col)
      const float* p = Wgate + j * ZSZ + kf * 32 + 8 * lkg; // 8 consecutive k
      bf16x8 tfr;
#pragma unroll
      for (int e = 0; e < 8; ++e) tfr[e] = (short)f2bf(p[e]);
      fragWg[kf][nf] = tfr;
    }
  }
  float biasG[2];
#pragma unroll
  for (int nf = 0; nf < 2; ++nf) biasG[nf] = bgate[gate_row + 16 * nf + lrow];

  bf16x8 fragWo[2];      // out-proj: wave owns 16 logit cols, K=64 -> 2 kf
#pragma unroll
  for (int kf = 0; kf < 2; ++kf) {
    int j = 16 * wv + lrow;                                  // logit col 0..127
    const float* p = Wout + j * HSZ + kf * 32 + 8 * lkg;
    bf16x8 tfr;
#pragma unroll
    for (int e = 0; e < 8; ++e) tfr[e] = (short)f2bf(p[e]);
    fragWo[kf] = tfr;
  }
  const float biasO = bout_[16 * wv + lrow];

  // ---- init h, c ----
  {
    int r = tid >> 5;            // 0..15
    int k = (tid & 31) * 2;      // 0..62
    float2 hv = *(const float2*)&h0[(b0 + r) * HSZ + k];
    float2 cv = *(const float2*)&c0[(b0 + r) * HSZ + k];
    c_lds[r * CLD + k]     = cv.x;
    c_lds[r * CLD + k + 1] = cv.y;
    z_lds[r * ZLD + ISZ + k]     = f2bf(hv.x);
    z_lds[r * ZLD + ISZ + k + 1] = f2bf(hv.y);
  }

  // ---- prefetch x[0] into registers ----
  const int xrow = tid >> 5;     // 0..15
  const int xc4  = tid & 31;     // float4 column
  f32x4 xr = *(const f32x4*)&x[(size_t)(b0 + xrow) * ISZ + xc4 * 4];

  const size_t probs_elems = (size_t)T_STEPS * BATCH * VSZ;

  for (int t = 0; t < T_STEPS; ++t) {
    // stage x[t] (from prefetch regs) into z_lds as bf16
    {
      u16x4 pk;
      pk[0] = f2bf(xr[0]); pk[1] = f2bf(xr[1]);
      pk[2] = f2bf(xr[2]); pk[3] = f2bf(xr[3]);
      *(u16x4*)&z_lds[xrow * ZLD + xc4 * 4] = pk;
    }
    __syncthreads();   // (1) z complete (x part + h part from prev step)

    // prefetch x[t+1] under the compute
    if (t + 1 < T_STEPS) {
      xr = *(const f32x4*)&x[(size_t)(t + 1) * BATCH * ISZ +
                             (size_t)(b0 + xrow) * ISZ + xc4 * 4];
    }

    // ---- gate GEMM: [16,192] x [192,32] per wave ----
    f32x4 acc0 = {biasG[0], biasG[0], biasG[0], biasG[0]};
    f32x4 acc1 = {biasG[1], biasG[1], biasG[1], biasG[1]};
#pragma unroll
    for (int kf = 0; kf < 6; ++kf) {
      const bf16x8 a = *(const bf16x8*)&z_lds[lrow * ZLD + kf * 32 + 8 * lkg];
      acc0 = __builtin_amdgcn_mfma_f32_16x16x32_bf16(a, fragWg[kf][0], acc0, 0, 0, 0);
      acc1 = __builtin_amdgcn_mfma_f32_16x16x32_bf16(a, fragWg[kf][1], acc1, 0, 0, 0);
    }

    // activations -> g_lds
#pragma unroll
    for (int nf = 0; nf < 2; ++nf) {
      const f32x4 a = nf ? acc1 : acc0;
      int jcol = gate_row + 16 * nf + lrow;   // 0..63 within gate
#pragma unroll
      for (int e = 0; e < 4; ++e) {
        int r = 4 * lkg + e;
        float gv = a[e];
        float av = (gate == 2) ? ftanh(gv) : fsigmoid(gv);
        g_lds[(gate * MBLK + r) * GLD + jcol] = av;
      }
    }
    __syncthreads();   // (2) gates ready; z reads done

    // ---- LSTM cell state update (2 elems per thread) ----
    {
      int r = tid >> 5;
      int k = (tid & 31) * 2;
      bool last = (t == T_STEPS - 1);
#pragma unroll
      for (int e = 0; e < 2; ++e) {
        int kk = k + e;
        float f  = g_lds[(0 * MBLK + r) * GLD + kk];
        float ii = g_lds[(1 * MBLK + r) * GLD + kk];
        float cd = g_lds[(2 * MBLK + r) * GLD + kk];
        float o  = g_lds[(3 * MBLK + r) * GLD + kk];
        float c  = c_lds[r * CLD + kk];
        c = c * f + cd * ii;
        float h = ftanh(c) * o;
        c_lds[r * CLD + kk] = c;
        z_lds[r * ZLD + ISZ + kk] = f2bf(h);
        if (last) {
          out[probs_elems + (size_t)(b0 + r) * HSZ + kk] = h;                       // hT
          out[probs_elems + (size_t)BATCH * HSZ + (size_t)(b0 + r) * HSZ + kk] = c; // cT
        }
      }
    }
    __syncthreads();   // (3) h (bf16) ready for out-proj

    // ---- output projection: [16,64] x [64,16] per wave ----
    f32x4 accO = {biasO, biasO, biasO, biasO};
#pragma unroll
    for (int kf = 0; kf < 2; ++kf) {
      const bf16x8 a = *(const bf16x8*)&z_lds[lrow * ZLD + ISZ + kf * 32 + 8 * lkg];
      accO = __builtin_amdgcn_mfma_f32_16x16x32_bf16(a, fragWo[kf], accO, 0, 0, 0);
    }
    {
      int col = 16 * wv + lrow;
#pragma unroll
      for (int e = 0; e < 4; ++e) {
        int r = 4 * lkg + e;
        l_lds[r * LLD + col] = accO[e];
      }
    }
    __syncthreads();   // (4) logits ready

    // ---- softmax over 128 cols (32 threads per row, 4 cols each) ----
    {
      int r  = tid >> 5;
      int cc = (tid & 31) * 4;
      f32x4 v = *(f32x4*)&l_lds[r * LLD + cc];
      float m = fmaxf(fmaxf(v[0], v[1]), fmaxf(v[2], v[3]));
#pragma unroll
      for (int off = 1; off < 32; off <<= 1) m = fmaxf(m, __shfl_xor(m, off));
      float e0 = __expf(v[0] - m), e1 = __expf(v[1] - m);
      float e2 = __expf(v[2] - m), e3 = __expf(v[3] - m);
      float s = e0 + e1 + e2 + e3;
#pragma unroll
      for (int off = 1; off < 32; off <<= 1) s += __shfl_xor(s, off);
      float inv = 1.0f / s;
      f32x4 pv = {e0 * inv, e1 * inv, e2 * inv, e3 * inv};
      *(f32x4*)&out[(size_t)t * BATCH * VSZ + (size_t)(b0 + r) * VSZ + cc] = pv;
    }
    // no trailing barrier needed: next iter's barrier (1) orders l_lds reuse,
    // and next x-write touches z cols 0..127 which have no readers after (2).
  }
}

extern "C" void kernel_launch(void* const* d_in, const int* in_sizes, int n_in,
                              void* d_out, int out_size, void* d_ws, size_t ws_size,
                              hipStream_t stream) {
  const float* x    = (const float*)d_in[0];
  const float* h0   = (const float*)d_in[1];
  const float* c0   = (const float*)d_in[2];
  const float* Wf   = (const float*)d_in[3];
  const float* bf_  = (const float*)d_in[4];
  const float* Wif  = (const float*)d_in[5];
  const float* bif_ = (const float*)d_in[6];
  const float* Wic  = (const float*)d_in[7];
  const float* bic_ = (const float*)d_in[8];
  const float* Wo   = (const float*)d_in[9];
  const float* bo_  = (const float*)d_in[10];
  const float* Wout = (const float*)d_in[11];
  const float* bout = (const float*)d_in[12];
  float* out = (float*)d_out;

  hipLaunchKernelGGL(lstm_kernel, dim3(BATCH / MBLK), dim3(NTHREADS), 0, stream,
                     x, h0, c0, Wf, bf_, Wif, bif_, Wic, bic_, Wo, bo_, Wout, bout, out);
}